// Round 23
// baseline (152.228 us; speedup 1.0000x reference)
//
#include <hip/hip_runtime.h>
#include <math.h>

#define BB 8
#define CH 128
#define HH 64
#define WWID 64
#define HIN 62
#define WIN 62
#define SPIN (HIN*WIN)      // 3844
#define HP 66
#define WP 66
#define GP2 70              // padded + 2-guard each side
#define NPIX (BB*HH*WWID)   // 32768
#define ASTRIDE 136         // LDS A-tile row stride in halfs
#define XPHALFS ((size_t)BB*GP2*GP2*CH)   // 5,017,600 halfs

typedef _Float16 v8h __attribute__((ext_vector_type(8)));
typedef float    v4f __attribute__((ext_vector_type(4)));
typedef float    f4a __attribute__((ext_vector_type(4), aligned(4)));

__device__ inline int xcd_swizzle(int bid, int nblk8) {
    return (bid & 7) * nblk8 + (bid >> 3);
}

// ---- P0: pack weights into MFMA B-frag order + dwT ------------------------
// R17-verified: border-zero lives in gA's grid; p0 = pack + dwT.
__global__ __launch_bounds__(256) void p0_pack(const float* __restrict__ conv_w,
                                               const float* __restrict__ in_proj_w,
                                               const float* __restrict__ off_w,
                                               const float* __restrict__ mask_w,
                                               const float* __restrict__ out_proj_w,
                                               const float* __restrict__ dw_w,
                                               _Float16* __restrict__ wp,
                                               float* __restrict__ dwT) {
    int t = threadIdx.x;
    int blk = blockIdx.x;
    if (blk == 31) {                                 // dwT[tap][c] transpose
        if (t < 128) {
            #pragma unroll
            for (int tap = 0; tap < 9; tap++) dwT[tap * 128 + t] = dw_w[t * 9 + tap];
        }
        return;
    }
    int tid = blk * 256 + t;                         // 0..7935
    int mat, base;
    if (tid < 2048)      { mat = 0; base = 0; }
    else if (tid < 4096) { mat = 1; base = 2048; }
    else if (tid < 5888) { mat = 2; base = 4096; }
    else                 { mat = 3; base = 5888; }
    int fi = tid - base;
    int nt = fi >> 8, rem = fi & 255, kc = rem >> 6, lane = rem & 63;
    int n = nt * 16 + (lane & 15);
    int kbase = kc * 32 + ((lane >> 4) & 3) * 8;
    _Float16* dst = wp + (size_t)tid * 8;
    #pragma unroll
    for (int j = 0; j < 8; j++) {
        int k = kbase + j;
        float v;
        if (mat == 0)      v = conv_w[n * CH + k];
        else if (mat == 1) v = in_proj_w[k * CH + n];
        else if (mat == 2) v = (n < 72) ? off_w[k * 72 + n]
                               : (n < 108 ? mask_w[k * 36 + (n - 72)] : 0.f);
        else               v = out_proj_w[k * CH + n];
        dst[j] = (_Float16)v;
    }
}

// ---- MFMA core: wave wv -> mt=wv>>1, ntb=(wv&1)*4 --------------------------
__device__ inline void mfma_loop8(const _Float16* __restrict__ a16,
                                  const _Float16* __restrict__ wp,
                                  v4f acc[4], int t) {
    int lane = t & 63;
    int wv = t >> 6;
    int mt = wv >> 1, ntb = (wv & 1) * 4;
    const _Float16* abase = a16 + (mt * 16 + (lane & 15)) * ASTRIDE + ((lane >> 4) * 8);
    #pragma unroll
    for (int kc = 0; kc < 4; kc++) {
        v8h av = *(const v8h*)(abase + kc * 32);
        #pragma unroll
        for (int j = 0; j < 4; j++) {
            v8h bv = *(const v8h*)(wp + ((size_t)((ntb + j) * 4 + kc) * 64 + lane) * 8);
            acc[j] = __builtin_amdgcn_mfma_f32_16x16x32_f16(av, bv, acc[j], 0, 0, 0);
        }
    }
}

__device__ inline void acc_to_a16_8(_Float16* a16, v4f acc[4], int t) {
    int lane = t & 63, ncol = lane & 15;
    int wv = t >> 6;
    int m0 = (wv >> 1) * 16 + ((lane >> 4) * 4);
    int ntb = (wv & 1) * 4;
    #pragma unroll
    for (int j = 0; j < 4; j++)
        #pragma unroll
        for (int r = 0; r < 4; r++)
            a16[(m0 + r) * ASTRIDE + (ntb + j) * 16 + ncol] = (_Float16)acc[j][r];
}

// ---- gA: fused conv1x1(pad=1) + in_proj; 32 px/block, 256 thr --------------
// Blocks >= 1024 zero the xpad16 border (disjoint from interior writes).
__global__ __launch_bounds__(256) void gA_conv_inproj(const float* __restrict__ x,
                                                      const _Float16* __restrict__ wp_conv,
                                                      const _Float16* __restrict__ wp_in,
                                                      const float* __restrict__ conv_b,
                                                      const float* __restrict__ in_b,
                                                      _Float16* __restrict__ y16,
                                                      _Float16* __restrict__ xpad16) {
    __shared__ _Float16 a16[32 * ASTRIDE];          // 8.7 KB
    int t = threadIdx.x;
    if (blockIdx.x >= 1024) {                        // border-zero blocks
        int tid2 = (blockIdx.x - 1024) * 256 + t;    // 0..8191
        // 8 batches x 804 border px x 16 v8h (128 ch) = 102912 v8h units
        for (int i = tid2; i < 102912; i += 8192) {
            int v8  = i & 15;
            int pid = i >> 4;                        // 0..6431
            int bb  = pid / 804;
            int p   = pid - bb * 804;
            int row, col;
            if (p < 420) {                           // rows {0,1,2,67,68,69} full width
                int r6 = p / 70;
                row = (r6 < 3) ? r6 : 64 + r6;
                col = p - r6 * 70;
            } else {                                 // rows 3..66, cols {0,1,2,67,68,69}
                int q  = p - 420;
                int rr = q / 6;
                int c6 = q - rr * 6;
                row = rr + 3;
                col = (c6 < 3) ? c6 : 64 + c6;
            }
            *(v8h*)&xpad16[(size_t)(((bb * GP2 + row) * GP2 + col) * CH) + v8 * 8] = (v8h)(_Float16)0;
        }
        return;
    }
    int eff = xcd_swizzle(blockIdx.x, 128);
    int pix0 = eff * 32;
    int h = (pix0 >> 6) & 63, b = pix0 >> 12, wb = pix0 & 63;
    bool hin = (h >= 1 && h <= 62);
    for (int q = t; q < 1024; q += 256) {
        int c = q >> 3, w4l = (q & 7) * 4;
        int w4 = wb + w4l;
        float4 v = make_float4(0.f, 0.f, 0.f, 0.f);
        if (hin) {
            const float* xr = x + ((size_t)(b * CH + c)) * SPIN + (h - 1) * WIN;
            if (w4 == 0)       { f4a e = *(const f4a*)&xr[0];      v = make_float4(0.f, e[0], e[1], e[2]); }
            else if (w4 == 60) { f4a e = *(const f4a*)&xr[58];     v = make_float4(e[1], e[2], e[3], 0.f); }
            else               { f4a e = *(const f4a*)&xr[w4 - 1]; v = make_float4(e[0], e[1], e[2], e[3]); }
        }
        a16[(w4l + 0) * ASTRIDE + c] = (_Float16)v.x;
        a16[(w4l + 1) * ASTRIDE + c] = (_Float16)v.y;
        a16[(w4l + 2) * ASTRIDE + c] = (_Float16)v.z;
        a16[(w4l + 3) * ASTRIDE + c] = (_Float16)v.w;
    }
    __syncthreads();
    int lane = t & 63, ncol = lane & 15;
    int ntb = ((t >> 6) & 1) * 4;
    v4f acc[4];
    #pragma unroll
    for (int j = 0; j < 4; j++) {
        float bv = conv_b[(ntb + j) * 16 + ncol];
        acc[j] = (v4f){bv, bv, bv, bv};
    }
    mfma_loop8(a16, wp_conv, acc, t);
    __syncthreads();
    acc_to_a16_8(a16, acc, t);                      // a16 = y tile
    __syncthreads();
    {
        _Float16* dst = y16 + (size_t)pix0 * CH;
        for (int q = t; q < 512; q += 256)
            *(v8h*)&dst[q * 8] = *(const v8h*)&a16[(q >> 4) * ASTRIDE + (q & 15) * 8];
    }
    v4f acc2[4];
    #pragma unroll
    for (int j = 0; j < 4; j++) {
        float bv = in_b[(ntb + j) * 16 + ncol];
        acc2[j] = (v4f){bv, bv, bv, bv};
    }
    mfma_loop8(a16, wp_in, acc2, t);
    __syncthreads();
    acc_to_a16_8(a16, acc2, t);                     // a16 = x_proj tile
    __syncthreads();
    {
        _Float16* dst = xpad16 + (size_t)(((b * GP2) + h + 3) * GP2 + 3 + wb) * CH;
        for (int q = t; q < 512; q += 256)
            *(v8h*)&dst[q * 8] = *(const v8h*)&a16[(q >> 4) * ASTRIDE + (q & 15) * 8];
    }
}

// ---- gF: dw3x3+LN+GELU+off/mask MFMA+softmax+taps+GATHER+out_proj+store ----
// FINAL LOCKED CONFIG — (512,2), VGPR 108, two-pass gather. Session evidence:
//  - R0 256-thr restructure & R18 (512,6): co-residency changes -> WRONG results
//  - R14 merged gather (8 v8h live): VGPR>128 -> 190MB scratch spill, 2.4x slower
//  - R21 merged gather (reg-budgeted, VGPR=128): correct, no spill, but NULL
//    (gF 48.8 vs 47.7) -> two-pass VALU dedup was not the critical path
//  - R16/R17 work shuffling between dispatches: null (fixed non-gF floor)
// gF is barrier/latency-bound at 2 blocks/CU; all safe levers explored.
__global__ __launch_bounds__(512, 2) void gF_mega(const _Float16* __restrict__ y16,
                                                  const _Float16* __restrict__ xpad16,
                                                  const _Float16* __restrict__ wp_om,
                                                  const _Float16* __restrict__ wp_out,
                                                  const float* __restrict__ dwT,
                                                  const float* __restrict__ dw_b,
                                                  const float* __restrict__ ln_g,
                                                  const float* __restrict__ ln_b,
                                                  const float* __restrict__ off_b,
                                                  const float* __restrict__ mask_b,
                                                  const float* __restrict__ out_b,
                                                  float* __restrict__ out) {
    __shared__ char smem[49920];
    _Float16* ylds = (_Float16*)smem;               // v8h idx: (r*16+c8)*65 + w
    int t = threadIdx.x;
    int eff = xcd_swizzle(blockIdx.x, 64);
    int pix0 = eff * 64;
    int h = (pix0 >> 6) & 63, b = pix0 >> 12;
    if (h == 0 || h == 63) {
        for (int i = t; i < 3120; i += 512) *(v8h*)&ylds[i * 8] = (v8h)(_Float16)0;
        __syncthreads();
    }
    for (int idx = t; idx < 3072; idx += 512) {
        int r = idx >> 10, w = (idx >> 4) & 63, c8 = idx & 15;
        int hh = h + r - 1;
        if (hh >= 0 && hh <= 63) {
            v8h v = *(const v8h*)&y16[(size_t)(((b * 64 + hh) * 64 + w) * CH) + c8 * 8];
            *(v8h*)&ylds[(size_t)((r * 16 + c8) * 65 + w) * 8] = v;
        }
    }
    __syncthreads();
    int px = t >> 3, q8 = t & 7;
    float acc[16];
    #pragma unroll
    for (int cb = 0; cb < 4; cb++) *(float4*)&acc[cb * 4] = *(const float4*)&dw_b[q8 * 16 + cb * 4];
    #pragma unroll
    for (int r = 0; r < 3; r++) {
        #pragma unroll
        for (int kx = 0; kx < 3; kx++) {
            int wq = px + kx - 1;
            bool valid = (wq >= 0 && wq <= 63);
            int wpc = min(max(wq, 0), 63);
            int tap = r * 3 + kx;
            if (valid) {
                #pragma unroll
                for (int cb = 0; cb < 2; cb++) {
                    v8h yv = *(const v8h*)&ylds[(size_t)((r * 16 + q8 * 2 + cb) * 65 + wpc) * 8];
                    float4 wa  = *(const float4*)&dwT[tap * 128 + q8 * 16 + cb * 8];
                    float4 wbv = *(const float4*)&dwT[tap * 128 + q8 * 16 + cb * 8 + 4];
                    acc[cb*8+0] += (float)yv[0] * wa.x;  acc[cb*8+1] += (float)yv[1] * wa.y;
                    acc[cb*8+2] += (float)yv[2] * wa.z;  acc[cb*8+3] += (float)yv[3] * wa.w;
                    acc[cb*8+4] += (float)yv[4] * wbv.x; acc[cb*8+5] += (float)yv[5] * wbv.y;
                    acc[cb*8+6] += (float)yv[6] * wbv.z; acc[cb*8+7] += (float)yv[7] * wbv.w;
                }
            }
        }
    }
    float s = 0.f, ss = 0.f;
    #pragma unroll
    for (int j = 0; j < 16; j++) { s += acc[j]; ss += acc[j] * acc[j]; }
    s  += __shfl_xor(s, 1);  s  += __shfl_xor(s, 2);  s  += __shfl_xor(s, 4);
    ss += __shfl_xor(ss, 1); ss += __shfl_xor(ss, 2); ss += __shfl_xor(ss, 4);
    float mu = s * (1.f / 128.f);
    float var = ss * (1.f / 128.f) - mu * mu;
    float rstd = rsqrtf(var + 1e-5f);
    v8h dreg[2];
    #pragma unroll
    for (int cb = 0; cb < 2; cb++) {
        float4 ga = *(const float4*)&ln_g[q8 * 16 + cb * 8];
        float4 gb = *(const float4*)&ln_g[q8 * 16 + cb * 8 + 4];
        float4 ba = *(const float4*)&ln_b[q8 * 16 + cb * 8];
        float4 bb = *(const float4*)&ln_b[q8 * 16 + cb * 8 + 4];
        float gv[8] = {ga.x, ga.y, ga.z, ga.w, gb.x, gb.y, gb.z, gb.w};
        float bv[8] = {ba.x, ba.y, ba.z, ba.w, bb.x, bb.y, bb.z, bb.w};
        #pragma unroll
        for (int j = 0; j < 8; j++) {
            float xln = (acc[cb * 8 + j] - mu) * rstd * gv[j] + bv[j];
            float gel = 0.5f * xln * (1.f + erff(xln * 0.70710678118654752f));
            dreg[cb][j] = (_Float16)gel;
        }
    }
    __syncthreads();                                // ylds dead
    _Float16* a16 = (_Float16*)smem;                // [0, 17408)
    float* om = (float*)(smem + 17408);             // [17408, 46080): 64 x 112 f32
    #pragma unroll
    for (int cb = 0; cb < 2; cb++)
        *(v8h*)&a16[px * ASTRIDE + q8 * 16 + cb * 8] = dreg[cb];
    __syncthreads();
    int lane = t & 63, ncol = lane & 15;
    int ntb = ((t >> 6) & 1) * 4;
    {
        v4f macc[4];
        #pragma unroll
        for (int j = 0; j < 4; j++) {
            int n = (ntb + j) * 16 + ncol;
            float bv = (n < 72) ? off_b[n] : (n < 108 ? mask_b[n - 72] : 0.f);
            macc[j] = (v4f){bv, bv, bv, bv};
        }
        mfma_loop8(a16, wp_om, macc, t);
        int m0 = ((t >> 6) >> 1) * 16 + ((lane >> 4) * 4);
        #pragma unroll
        for (int j = 0; j < 4; j++) {
            if (ntb + j < 7) {
                #pragma unroll
                for (int r = 0; r < 4; r++)
                    om[(m0 + r) * 112 + (ntb + j) * 16 + ncol] = macc[j][r];
            }
        }
    }
    __syncthreads();
    // ---- softmax + taps + gather: px = t>>3, slot s8 = t&7 -> 16 ch --------
    // Two sequential 8-ch passes (VGPR 108; merged variant R21 = null).
    {
        int s8 = t & 7;
        int ch = s8 * 16, g = s8 >> 1;              // group = ch/32
        const float* row = &om[px * 112];
        float lg[9];
        #pragma unroll
        for (int i = 0; i < 9; i++) lg[i] = row[72 + g * 9 + i];
        float mx = lg[0];
        #pragma unroll
        for (int i = 1; i < 9; i++) mx = fmaxf(mx, lg[i]);
        float e[9], sum = 0.f;
        #pragma unroll
        for (int i = 0; i < 9; i++) { e[i] = expf(lg[i] - mx); sum += e[i]; }
        float inv = 1.f / sum;
        #pragma unroll
        for (int half = 0; half < 2; half++) {
            const _Float16* base = xpad16 + (size_t)b * GP2 * GP2 * CH + ch + half * 8;
            float gacc[8];
            #pragma unroll
            for (int j = 0; j < 8; j++) gacc[j] = 0.f;
            #pragma unroll
            for (int p = 0; p < 9; p++) {
                float offx = row[(g * 9 + p) * 2];
                float offy = row[(g * 9 + p) * 2 + 1];
                float m = e[p] * inv;
                float ix = (float)(px + (p / 3)) + offx;
                float iy = (float)(h + (p % 3)) + offy;
                ix = fminf(fmaxf(ix, -2.f), (float)(WP + 1));
                iy = fminf(fmaxf(iy, -2.f), (float)(HP + 1));
                float x0f = floorf(ix), y0f = floorf(iy);
                float fx = ix - x0f, fy = iy - y0f;
                int x0 = (int)x0f, y0 = (int)y0f;
                int off = ((y0 + 2) * GP2 + (x0 + 2)) * CH;
                float w11 = fx * fy;
                float w10 = fx - w11;
                float w01 = fy - w11;
                float w00 = 1.f - fx - fy + w11;
                w00 *= m; w10 *= m; w01 *= m; w11 *= m;
                v8h h0 = *(const v8h*)&base[off];
                v8h h1 = *(const v8h*)&base[off + CH];
                v8h h2 = *(const v8h*)&base[off + GP2 * CH];
                v8h h3 = *(const v8h*)&base[off + GP2 * CH + CH];
                #pragma unroll
                for (int j = 0; j < 8; j++)
                    gacc[j] += w00*(float)h0[j] + w10*(float)h1[j] + w01*(float)h2[j] + w11*(float)h3[j];
            }
            v8h r0;
            #pragma unroll
            for (int j = 0; j < 8; j++) r0[j] = (_Float16)gacc[j];
            *(v8h*)&a16[px * ASTRIDE + ch + half * 8] = r0;   // a16 = core tile
        }
    }
    __syncthreads();
    // ---- out_proj MFMA + NCHW store ----
    {
        v4f oacc[4];
        #pragma unroll
        for (int j = 0; j < 4; j++) {
            float bv = out_b[(ntb + j) * 16 + ncol];
            oacc[j] = (v4f){bv, bv, bv, bv};
        }
        mfma_loop8(a16, wp_out, oacc, t);
        __syncthreads();                             // a16 reads done
        float* res = (float*)smem;                   // 128 x 68 f32 = 34816 B
        int m0 = ((t >> 6) >> 1) * 16 + ((lane >> 4) * 4);
        #pragma unroll
        for (int j = 0; j < 4; j++)
            #pragma unroll
            for (int r = 0; r < 4; r++)
                res[((ntb + j) * 16 + ncol) * 68 + (m0 + r)] = oacc[j][r];
        __syncthreads();
        for (int q = t; q < 2048; q += 512) {
            int cc = q >> 4, w4 = (q & 15) * 4;
            float4 o = *(const float4*)&res[cc * 68 + w4];
            *(float4*)&out[(size_t)((b * CH + cc) * HH + h) * WWID + w4] = o;
        }
    }
}

extern "C" void kernel_launch(void* const* d_in, const int* in_sizes, int n_in,
                              void* d_out, int out_size, void* d_ws, size_t ws_size,
                              hipStream_t stream) {
    const float* x        = (const float*)d_in[0];
    const float* conv_w   = (const float*)d_in[1];
    const float* conv_b   = (const float*)d_in[2];
    const float* in_proj_w= (const float*)d_in[3];
    const float* in_proj_b= (const float*)d_in[4];
    const float* dw_w     = (const float*)d_in[5];
    const float* dw_b     = (const float*)d_in[6];
    const float* ln_g     = (const float*)d_in[7];
    const float* ln_b     = (const float*)d_in[8];
    const float* off_w    = (const float*)d_in[9];
    const float* off_b    = (const float*)d_in[10];
    const float* mask_w   = (const float*)d_in[11];
    const float* mask_b   = (const float*)d_in[12];
    const float* out_proj_w = (const float*)d_in[13];
    const float* out_proj_b = (const float*)d_in[14];
    float* out = (float*)d_out;

    float* ws = (float*)d_ws;
    const size_t O_WP   = 0;
    const size_t O_DWT  = 32768;
    const size_t O_Y16  = 34816;
    const size_t O_XP16 = O_Y16 + 2097152;
    _Float16* wp     = (_Float16*)(ws + O_WP);
    float*    dwT    = ws + O_DWT;
    _Float16* y16    = (_Float16*)(ws + O_Y16);
    _Float16* xpad16 = (_Float16*)(ws + O_XP16);

    _Float16* wp_conv = wp;
    _Float16* wp_in   = wp + (size_t)2048 * 8;
    _Float16* wp_om   = wp + (size_t)4096 * 8;
    _Float16* wp_out  = wp + (size_t)5888 * 8;

    p0_pack<<<32, 256, 0, stream>>>(conv_w, in_proj_w, off_w, mask_w, out_proj_w, dw_w, wp, dwT);
    gA_conv_inproj<<<1056, 256, 0, stream>>>(x, wp_conv, wp_in, conv_b, in_proj_b, y16, xpad16);
    gF_mega<<<NPIX / 64, 512, 0, stream>>>(y16, xpad16, wp_om, wp_out, dwT, dw_b,
                                           ln_g, ln_b, off_b, mask_b, out_proj_b, out);
}

// Round 24
// 150.747 us; speedup vs baseline: 1.0098x; 1.0098x over previous
//
#include <hip/hip_runtime.h>
#include <math.h>

#define BB 8
#define CH 128
#define HH 64
#define WWID 64
#define HIN 62
#define WIN 62
#define SPIN (HIN*WIN)      // 3844
#define HP 66
#define WP 66
#define GP2 70              // padded + 2-guard each side
#define NPIX (BB*HH*WWID)   // 32768
#define ASTRIDE 136         // LDS A-tile row stride in halfs
#define XPHALFS ((size_t)BB*GP2*GP2*CH)   // 5,017,600 halfs

typedef _Float16 v8h __attribute__((ext_vector_type(8)));
typedef float    v4f __attribute__((ext_vector_type(4)));
typedef float    f4a __attribute__((ext_vector_type(4), aligned(4)));

__device__ inline int xcd_swizzle(int bid, int nblk8) {
    return (bid & 7) * nblk8 + (bid >> 3);
}

// ---- P0: pack weights into MFMA B-frag order + dwT ------------------------
__global__ __launch_bounds__(256) void p0_pack(const float* __restrict__ conv_w,
                                               const float* __restrict__ in_proj_w,
                                               const float* __restrict__ off_w,
                                               const float* __restrict__ mask_w,
                                               const float* __restrict__ out_proj_w,
                                               const float* __restrict__ dw_w,
                                               _Float16* __restrict__ wp,
                                               float* __restrict__ dwT) {
    int t = threadIdx.x;
    int blk = blockIdx.x;
    if (blk == 31) {                                 // dwT[tap][c] transpose
        if (t < 128) {
            #pragma unroll
            for (int tap = 0; tap < 9; tap++) dwT[tap * 128 + t] = dw_w[t * 9 + tap];
        }
        return;
    }
    int tid = blk * 256 + t;                         // 0..7935
    int mat, base;
    if (tid < 2048)      { mat = 0; base = 0; }
    else if (tid < 4096) { mat = 1; base = 2048; }
    else if (tid < 5888) { mat = 2; base = 4096; }
    else                 { mat = 3; base = 5888; }
    int fi = tid - base;
    int nt = fi >> 8, rem = fi & 255, kc = rem >> 6, lane = rem & 63;
    int n = nt * 16 + (lane & 15);
    int kbase = kc * 32 + ((lane >> 4) & 3) * 8;
    _Float16* dst = wp + (size_t)tid * 8;
    #pragma unroll
    for (int j = 0; j < 8; j++) {
        int k = kbase + j;
        float v;
        if (mat == 0)      v = conv_w[n * CH + k];
        else if (mat == 1) v = in_proj_w[k * CH + n];
        else if (mat == 2) v = (n < 72) ? off_w[k * 72 + n]
                               : (n < 108 ? mask_w[k * 36 + (n - 72)] : 0.f);
        else               v = out_proj_w[k * CH + n];
        dst[j] = (_Float16)v;
    }
}

// ---- MFMA core: wave wv -> mt=wv>>1, ntb=(wv&1)*4 --------------------------
// With 512 threads (8 waves) covers M=64; with 256 threads covers M=32.
__device__ inline void mfma_loop8(const _Float16* __restrict__ a16,
                                  const _Float16* __restrict__ wp,
                                  v4f acc[4], int t) {
    int lane = t & 63;
    int wv = t >> 6;
    int mt = wv >> 1, ntb = (wv & 1) * 4;
    const _Float16* abase = a16 + (mt * 16 + (lane & 15)) * ASTRIDE + ((lane >> 4) * 8);
    #pragma unroll
    for (int kc = 0; kc < 4; kc++) {
        v8h av = *(const v8h*)(abase + kc * 32);
        #pragma unroll
        for (int j = 0; j < 4; j++) {
            v8h bv = *(const v8h*)(wp + ((size_t)((ntb + j) * 4 + kc) * 64 + lane) * 8);
            acc[j] = __builtin_amdgcn_mfma_f32_16x16x32_f16(av, bv, acc[j], 0, 0, 0);
        }
    }
}

__device__ inline void acc_to_a16_8(_Float16* a16, v4f acc[4], int t) {
    int lane = t & 63, ncol = lane & 15;
    int wv = t >> 6;
    int m0 = (wv >> 1) * 16 + ((lane >> 4) * 4);
    int ntb = (wv & 1) * 4;
    #pragma unroll
    for (int j = 0; j < 4; j++)
        #pragma unroll
        for (int r = 0; r < 4; r++)
            a16[(m0 + r) * ASTRIDE + (ntb + j) * 16 + ncol] = (_Float16)acc[j][r];
}

// ---- gA: fused conv1x1(pad=1) + in_proj; R24: 64 px/block, 512 thr ---------
// One block = one full h-row (M=64 MFMA tile). Reuses the gF-verified
// 512-thread mfma_loop8/acc_to_a16_8 path (wv 0..7 -> mt 0..3). Halves
// barrier instances vs the 32-px/256-thr version. Blocks >= 512 zero the
// xpad16 border. gF untouched (fragile; see its header).
__global__ __launch_bounds__(512) void gA_conv_inproj(const float* __restrict__ x,
                                                      const _Float16* __restrict__ wp_conv,
                                                      const _Float16* __restrict__ wp_in,
                                                      const float* __restrict__ conv_b,
                                                      const float* __restrict__ in_b,
                                                      _Float16* __restrict__ y16,
                                                      _Float16* __restrict__ xpad16) {
    __shared__ _Float16 a16[64 * ASTRIDE];          // 17.4 KB
    int t = threadIdx.x;
    if (blockIdx.x >= 512) {                         // border-zero blocks (32)
        int tid2 = (blockIdx.x - 512) * 512 + t;     // 0..16383
        // 8 batches x 804 border px x 16 v8h (128 ch) = 102912 v8h units
        for (int i = tid2; i < 102912; i += 16384) {
            int v8  = i & 15;
            int pid = i >> 4;                        // 0..6431
            int bb  = pid / 804;
            int p   = pid - bb * 804;
            int row, col;
            if (p < 420) {                           // rows {0,1,2,67,68,69} full width
                int r6 = p / 70;
                row = (r6 < 3) ? r6 : 64 + r6;
                col = p - r6 * 70;
            } else {                                 // rows 3..66, cols {0,1,2,67,68,69}
                int q  = p - 420;
                int rr = q / 6;
                int c6 = q - rr * 6;
                row = rr + 3;
                col = (c6 < 3) ? c6 : 64 + c6;
            }
            *(v8h*)&xpad16[(size_t)(((bb * GP2 + row) * GP2 + col) * CH) + v8 * 8] = (v8h)(_Float16)0;
        }
        return;
    }
    int eff = xcd_swizzle(blockIdx.x, 64);           // 512 blocks -> row id
    int pix0 = eff * 64;                             // row-aligned (w spans 0..63)
    int h = (pix0 >> 6) & 63, b = pix0 >> 12;
    bool hin = (h >= 1 && h <= 62);
    // stage x row (padded w) as A-tile: a16[w][c], 2048 (c,w4) units
    for (int q = t; q < 2048; q += 512) {
        int c = q >> 4, w4 = (q & 15) * 4;           // w4 in {0,4,...,60}
        float4 v = make_float4(0.f, 0.f, 0.f, 0.f);
        if (hin) {
            const float* xr = x + ((size_t)(b * CH + c)) * SPIN + (h - 1) * WIN;
            if (w4 == 0)       { f4a e = *(const f4a*)&xr[0];      v = make_float4(0.f, e[0], e[1], e[2]); }
            else if (w4 == 60) { f4a e = *(const f4a*)&xr[58];     v = make_float4(e[1], e[2], e[3], 0.f); }
            else               { f4a e = *(const f4a*)&xr[w4 - 1]; v = make_float4(e[0], e[1], e[2], e[3]); }
        }
        a16[(w4 + 0) * ASTRIDE + c] = (_Float16)v.x;
        a16[(w4 + 1) * ASTRIDE + c] = (_Float16)v.y;
        a16[(w4 + 2) * ASTRIDE + c] = (_Float16)v.z;
        a16[(w4 + 3) * ASTRIDE + c] = (_Float16)v.w;
    }
    __syncthreads();
    int lane = t & 63, ncol = lane & 15;
    int ntb = ((t >> 6) & 1) * 4;
    v4f acc[4];
    #pragma unroll
    for (int j = 0; j < 4; j++) {
        float bv = conv_b[(ntb + j) * 16 + ncol];
        acc[j] = (v4f){bv, bv, bv, bv};
    }
    mfma_loop8(a16, wp_conv, acc, t);                // M=64 with 8 waves
    __syncthreads();
    acc_to_a16_8(a16, acc, t);                       // a16 = y tile (64 rows)
    __syncthreads();
    {
        _Float16* dst = y16 + (size_t)pix0 * CH;
        for (int q = t; q < 1024; q += 512)          // 64 px x 16 c8
            *(v8h*)&dst[q * 8] = *(const v8h*)&a16[(q >> 4) * ASTRIDE + (q & 15) * 8];
    }
    v4f acc2[4];
    #pragma unroll
    for (int j = 0; j < 4; j++) {
        float bv = in_b[(ntb + j) * 16 + ncol];
        acc2[j] = (v4f){bv, bv, bv, bv};
    }
    mfma_loop8(a16, wp_in, acc2, t);                 // reads y tile
    __syncthreads();                                 // all a16 reads done
    acc_to_a16_8(a16, acc2, t);                      // a16 = x_proj tile
    __syncthreads();
    {
        _Float16* dst = xpad16 + (size_t)(((b * GP2) + h + 3) * GP2 + 3) * CH;
        for (int q = t; q < 1024; q += 512)          // cols 3..66 contiguous
            *(v8h*)&dst[q * 8] = *(const v8h*)&a16[(q >> 4) * ASTRIDE + (q & 15) * 8];
    }
}

// ---- gF: dw3x3+LN+GELU+off/mask MFMA+softmax+taps+GATHER+out_proj+store ----
// LOCKED (512,2) / VGPR 108 / two-pass gather — verified PASS 5x
// (151.3/152.8/151.8/153.3/152.2us). Co-residency changes break numerics
// (R0/R18); VGPR>128 spills (R14); merged gather null (R21). DO NOT TOUCH.
__global__ __launch_bounds__(512, 2) void gF_mega(const _Float16* __restrict__ y16,
                                                  const _Float16* __restrict__ xpad16,
                                                  const _Float16* __restrict__ wp_om,
                                                  const _Float16* __restrict__ wp_out,
                                                  const float* __restrict__ dwT,
                                                  const float* __restrict__ dw_b,
                                                  const float* __restrict__ ln_g,
                                                  const float* __restrict__ ln_b,
                                                  const float* __restrict__ off_b,
                                                  const float* __restrict__ mask_b,
                                                  const float* __restrict__ out_b,
                                                  float* __restrict__ out) {
    __shared__ char smem[49920];
    _Float16* ylds = (_Float16*)smem;               // v8h idx: (r*16+c8)*65 + w
    int t = threadIdx.x;
    int eff = xcd_swizzle(blockIdx.x, 64);
    int pix0 = eff * 64;
    int h = (pix0 >> 6) & 63, b = pix0 >> 12;
    if (h == 0 || h == 63) {
        for (int i = t; i < 3120; i += 512) *(v8h*)&ylds[i * 8] = (v8h)(_Float16)0;
        __syncthreads();
    }
    for (int idx = t; idx < 3072; idx += 512) {
        int r = idx >> 10, w = (idx >> 4) & 63, c8 = idx & 15;
        int hh = h + r - 1;
        if (hh >= 0 && hh <= 63) {
            v8h v = *(const v8h*)&y16[(size_t)(((b * 64 + hh) * 64 + w) * CH) + c8 * 8];
            *(v8h*)&ylds[(size_t)((r * 16 + c8) * 65 + w) * 8] = v;
        }
    }
    __syncthreads();
    int px = t >> 3, q8 = t & 7;
    float acc[16];
    #pragma unroll
    for (int cb = 0; cb < 4; cb++) *(float4*)&acc[cb * 4] = *(const float4*)&dw_b[q8 * 16 + cb * 4];
    #pragma unroll
    for (int r = 0; r < 3; r++) {
        #pragma unroll
        for (int kx = 0; kx < 3; kx++) {
            int wq = px + kx - 1;
            bool valid = (wq >= 0 && wq <= 63);
            int wpc = min(max(wq, 0), 63);
            int tap = r * 3 + kx;
            if (valid) {
                #pragma unroll
                for (int cb = 0; cb < 2; cb++) {
                    v8h yv = *(const v8h*)&ylds[(size_t)((r * 16 + q8 * 2 + cb) * 65 + wpc) * 8];
                    float4 wa  = *(const float4*)&dwT[tap * 128 + q8 * 16 + cb * 8];
                    float4 wbv = *(const float4*)&dwT[tap * 128 + q8 * 16 + cb * 8 + 4];
                    acc[cb*8+0] += (float)yv[0] * wa.x;  acc[cb*8+1] += (float)yv[1] * wa.y;
                    acc[cb*8+2] += (float)yv[2] * wa.z;  acc[cb*8+3] += (float)yv[3] * wa.w;
                    acc[cb*8+4] += (float)yv[4] * wbv.x; acc[cb*8+5] += (float)yv[5] * wbv.y;
                    acc[cb*8+6] += (float)yv[6] * wbv.z; acc[cb*8+7] += (float)yv[7] * wbv.w;
                }
            }
        }
    }
    float s = 0.f, ss = 0.f;
    #pragma unroll
    for (int j = 0; j < 16; j++) { s += acc[j]; ss += acc[j] * acc[j]; }
    s  += __shfl_xor(s, 1);  s  += __shfl_xor(s, 2);  s  += __shfl_xor(s, 4);
    ss += __shfl_xor(ss, 1); ss += __shfl_xor(ss, 2); ss += __shfl_xor(ss, 4);
    float mu = s * (1.f / 128.f);
    float var = ss * (1.f / 128.f) - mu * mu;
    float rstd = rsqrtf(var + 1e-5f);
    v8h dreg[2];
    #pragma unroll
    for (int cb = 0; cb < 2; cb++) {
        float4 ga = *(const float4*)&ln_g[q8 * 16 + cb * 8];
        float4 gb = *(const float4*)&ln_g[q8 * 16 + cb * 8 + 4];
        float4 ba = *(const float4*)&ln_b[q8 * 16 + cb * 8];
        float4 bb = *(const float4*)&ln_b[q8 * 16 + cb * 8 + 4];
        float gv[8] = {ga.x, ga.y, ga.z, ga.w, gb.x, gb.y, gb.z, gb.w};
        float bv[8] = {ba.x, ba.y, ba.z, ba.w, bb.x, bb.y, bb.z, bb.w};
        #pragma unroll
        for (int j = 0; j < 8; j++) {
            float xln = (acc[cb * 8 + j] - mu) * rstd * gv[j] + bv[j];
            float gel = 0.5f * xln * (1.f + erff(xln * 0.70710678118654752f));
            dreg[cb][j] = (_Float16)gel;
        }
    }
    __syncthreads();                                // ylds dead
    _Float16* a16 = (_Float16*)smem;                // [0, 17408)
    float* om = (float*)(smem + 17408);             // [17408, 46080): 64 x 112 f32
    #pragma unroll
    for (int cb = 0; cb < 2; cb++)
        *(v8h*)&a16[px * ASTRIDE + q8 * 16 + cb * 8] = dreg[cb];
    __syncthreads();
    int lane = t & 63, ncol = lane & 15;
    int ntb = ((t >> 6) & 1) * 4;
    {
        v4f macc[4];
        #pragma unroll
        for (int j = 0; j < 4; j++) {
            int n = (ntb + j) * 16 + ncol;
            float bv = (n < 72) ? off_b[n] : (n < 108 ? mask_b[n - 72] : 0.f);
            macc[j] = (v4f){bv, bv, bv, bv};
        }
        mfma_loop8(a16, wp_om, macc, t);
        int m0 = ((t >> 6) >> 1) * 16 + ((lane >> 4) * 4);
        #pragma unroll
        for (int j = 0; j < 4; j++) {
            if (ntb + j < 7) {
                #pragma unroll
                for (int r = 0; r < 4; r++)
                    om[(m0 + r) * 112 + (ntb + j) * 16 + ncol] = macc[j][r];
            }
        }
    }
    __syncthreads();
    // ---- softmax + taps + gather: px = t>>3, slot s8 = t&7 -> 16 ch --------
    // Two sequential 8-ch passes (VGPR 108; merged variant R21 = null).
    {
        int s8 = t & 7;
        int ch = s8 * 16, g = s8 >> 1;              // group = ch/32
        const float* row = &om[px * 112];
        float lg[9];
        #pragma unroll
        for (int i = 0; i < 9; i++) lg[i] = row[72 + g * 9 + i];
        float mx = lg[0];
        #pragma unroll
        for (int i = 1; i < 9; i++) mx = fmaxf(mx, lg[i]);
        float e[9], sum = 0.f;
        #pragma unroll
        for (int i = 0; i < 9; i++) { e[i] = expf(lg[i] - mx); sum += e[i]; }
        float inv = 1.f / sum;
        #pragma unroll
        for (int half = 0; half < 2; half++) {
            const _Float16* base = xpad16 + (size_t)b * GP2 * GP2 * CH + ch + half * 8;
            float gacc[8];
            #pragma unroll
            for (int j = 0; j < 8; j++) gacc[j] = 0.f;
            #pragma unroll
            for (int p = 0; p < 9; p++) {
                float offx = row[(g * 9 + p) * 2];
                float offy = row[(g * 9 + p) * 2 + 1];
                float m = e[p] * inv;
                float ix = (float)(px + (p / 3)) + offx;
                float iy = (float)(h + (p % 3)) + offy;
                ix = fminf(fmaxf(ix, -2.f), (float)(WP + 1));
                iy = fminf(fmaxf(iy, -2.f), (float)(HP + 1));
                float x0f = floorf(ix), y0f = floorf(iy);
                float fx = ix - x0f, fy = iy - y0f;
                int x0 = (int)x0f, y0 = (int)y0f;
                int off = ((y0 + 2) * GP2 + (x0 + 2)) * CH;
                float w11 = fx * fy;
                float w10 = fx - w11;
                float w01 = fy - w11;
                float w00 = 1.f - fx - fy + w11;
                w00 *= m; w10 *= m; w01 *= m; w11 *= m;
                v8h h0 = *(const v8h*)&base[off];
                v8h h1 = *(const v8h*)&base[off + CH];
                v8h h2 = *(const v8h*)&base[off + GP2 * CH];
                v8h h3 = *(const v8h*)&base[off + GP2 * CH + CH];
                #pragma unroll
                for (int j = 0; j < 8; j++)
                    gacc[j] += w00*(float)h0[j] + w10*(float)h1[j] + w01*(float)h2[j] + w11*(float)h3[j];
            }
            v8h r0;
            #pragma unroll
            for (int j = 0; j < 8; j++) r0[j] = (_Float16)gacc[j];
            *(v8h*)&a16[px * ASTRIDE + ch + half * 8] = r0;   // a16 = core tile
        }
    }
    __syncthreads();
    // ---- out_proj MFMA + NCHW store ----
    {
        v4f oacc[4];
        #pragma unroll
        for (int j = 0; j < 4; j++) {
            float bv = out_b[(ntb + j) * 16 + ncol];
            oacc[j] = (v4f){bv, bv, bv, bv};
        }
        mfma_loop8(a16, wp_out, oacc, t);
        __syncthreads();                             // a16 reads done
        float* res = (float*)smem;                   // 128 x 68 f32 = 34816 B
        int m0 = ((t >> 6) >> 1) * 16 + ((lane >> 4) * 4);
        #pragma unroll
        for (int j = 0; j < 4; j++)
            #pragma unroll
            for (int r = 0; r < 4; r++)
                res[((ntb + j) * 16 + ncol) * 68 + (m0 + r)] = oacc[j][r];
        __syncthreads();
        for (int q = t; q < 2048; q += 512) {
            int cc = q >> 4, w4 = (q & 15) * 4;
            float4 o = *(const float4*)&res[cc * 68 + w4];
            *(float4*)&out[(size_t)((b * CH + cc) * HH + h) * WWID + w4] = o;
        }
    }
}

extern "C" void kernel_launch(void* const* d_in, const int* in_sizes, int n_in,
                              void* d_out, int out_size, void* d_ws, size_t ws_size,
                              hipStream_t stream) {
    const float* x        = (const float*)d_in[0];
    const float* conv_w   = (const float*)d_in[1];
    const float* conv_b   = (const float*)d_in[2];
    const float* in_proj_w= (const float*)d_in[3];
    const float* in_proj_b= (const float*)d_in[4];
    const float* dw_w     = (const float*)d_in[5];
    const float* dw_b     = (const float*)d_in[6];
    const float* ln_g     = (const float*)d_in[7];
    const float* ln_b     = (const float*)d_in[8];
    const float* off_w    = (const float*)d_in[9];
    const float* off_b    = (const float*)d_in[10];
    const float* mask_w   = (const float*)d_in[11];
    const float* mask_b   = (const float*)d_in[12];
    const float* out_proj_w = (const float*)d_in[13];
    const float* out_proj_b = (const float*)d_in[14];
    float* out = (float*)d_out;

    float* ws = (float*)d_ws;
    const size_t O_WP   = 0;
    const size_t O_DWT  = 32768;
    const size_t O_Y16  = 34816;
    const size_t O_XP16 = O_Y16 + 2097152;
    _Float16* wp     = (_Float16*)(ws + O_WP);
    float*    dwT    = ws + O_DWT;
    _Float16* y16    = (_Float16*)(ws + O_Y16);
    _Float16* xpad16 = (_Float16*)(ws + O_XP16);

    _Float16* wp_conv = wp;
    _Float16* wp_in   = wp + (size_t)2048 * 8;
    _Float16* wp_om   = wp + (size_t)4096 * 8;
    _Float16* wp_out  = wp + (size_t)5888 * 8;

    p0_pack<<<32, 256, 0, stream>>>(conv_w, in_proj_w, off_w, mask_w, out_proj_w, dw_w, wp, dwT);
    gA_conv_inproj<<<544, 512, 0, stream>>>(x, wp_conv, wp_in, conv_b, in_proj_b, y16, xpad16);
    gF_mega<<<NPIX / 64, 512, 0, stream>>>(y16, xpad16, wp_om, wp_out, dwT, dw_b,
                                           ln_g, ln_b, off_b, mask_b, out_proj_b, out);
}